// Round 2
// baseline (274.389 us; speedup 1.0000x reference)
//
#include <hip/hip_runtime.h>
#include <hip/hip_bf16.h>
#include <math.h>

// KoLeo loss: B=8, T=4096, D=256 fp32 input.
// Phase 1: convert x -> bf16 (ws)
// Phase 2: per-batch Gram X·X^T via bf16 MFMA, streaming per-row argmax (diag excluded)
// Phase 3: exact fp32 distances to argmax neighbor, loss = -mean(log(dist+eps))

#define Bq 8
#define Tq 4096
#define Dq 256

typedef __attribute__((ext_vector_type(8))) short bf16x8;
typedef __attribute__((ext_vector_type(4))) float f32x4;

__device__ __forceinline__ unsigned short f2bf(float f) {
    unsigned int u = __float_as_uint(f);
    unsigned int r = (u + 0x7fffu + ((u >> 16) & 1u)) >> 16;   // RNE
    return (unsigned short)r;
}

// ---------------- Phase 1: fp32 -> bf16 ----------------
__global__ void cvt_kernel(const float* __restrict__ x, unsigned short* __restrict__ xb) {
    int i = blockIdx.x * blockDim.x + threadIdx.x;  // one float4 per thread
    const int n4 = Bq * Tq * Dq / 4;
    if (i < n4) {
        float4 v = ((const float4*)x)[i];
        ushort4 o;
        o.x = f2bf(v.x); o.y = f2bf(v.y); o.z = f2bf(v.z); o.w = f2bf(v.w);
        ((ushort4*)xb)[i] = o;
    }
}

// ---------------- Phase 2: Gram + streaming argmax ----------------
// Grid: 512 blocks = 8 batches x 64 row-tiles (batch = bid & 7 for XCD/L2 affinity).
//   -> 2 blocks/CU co-resident (VGPR <= 128, launch_bounds(512,4)) = 16 waves/CU.
// Block: 512 threads = 8 waves (2 M-waves x 4 N-waves).
// Block tile: 64 rows x (all 4096 cols, in 32 s-tiles of 128).
// Wave tile per s-tile: 32 rows (2 x 16) x 32 cols (2 x 16), K = 256 = 8 x 32.
// A fragments register-resident: afrag[8][2] = 16 x bf16x8 = 64 VGPR.
// mfma_f32_16x16x32_bf16 C/D layout: col = lane&15, row = (lane>>4)*4 + reg (verified).
// Exactly one s-tile per block contains the diagonal -> wave-uniform branch.
__global__ __launch_bounds__(512, 4)
void argmax_kernel(const unsigned short* __restrict__ xb, int* __restrict__ nn_idx) {
    const int bid   = blockIdx.x;
    const int batch = bid & 7;
    const int rowTile = bid >> 3;          // 0..63  (64-row tiles)
    const int tid  = threadIdx.x;
    const int lane = tid & 63;
    const int wave = tid >> 6;             // 0..7
    const int waveM = wave >> 2;           // 0..1
    const int waveN = wave & 3;            // 0..3
    const int lrow = lane & 15;            // A-row / B-col / C-col
    const int lk   = lane >> 4;            // k-group / C row-group

    const unsigned short* xB = xb + (size_t)batch * Tq * Dq;
    const int rowBase = rowTile * 64 + waveM * 32;
    const int diagSt = rowTile >> 1;       // the single s-tile containing s == t

    // A fragments, register resident: afrag[kk][mi]  (16 frags = 64 VGPR)
    bf16x8 afrag[8][2];
#pragma unroll
    for (int mi = 0; mi < 2; ++mi) {
        const unsigned short* rp = xB + (size_t)(rowBase + mi * 16 + lrow) * Dq + lk * 8;
#pragma unroll
        for (int kk = 0; kk < 8; ++kk)
            afrag[kk][mi] = *(const bf16x8*)(rp + kk * 32);
    }

    float best[2][4];   // [mi][j]
    int   bidx[2][4];
#pragma unroll
    for (int mi = 0; mi < 2; ++mi)
#pragma unroll
        for (int j = 0; j < 4; ++j) { best[mi][j] = -1e30f; bidx[mi][j] = 0; }

    for (int st = 0; st < 32; ++st) {
        const int sBase = st * 128 + waveN * 32;
        f32x4 acc[2][2];
#pragma unroll
        for (int mi = 0; mi < 2; ++mi)
#pragma unroll
            for (int ni = 0; ni < 2; ++ni)
                acc[mi][ni] = (f32x4){0.f, 0.f, 0.f, 0.f};

#pragma unroll
        for (int kk = 0; kk < 8; ++kk) {
            bf16x8 bfr[2];
#pragma unroll
            for (int ni = 0; ni < 2; ++ni) {
                const int s = sBase + ni * 16 + lrow;
                bfr[ni] = *(const bf16x8*)(xB + (size_t)s * Dq + kk * 32 + lk * 8);
            }
#pragma unroll
            for (int mi = 0; mi < 2; ++mi)
#pragma unroll
                for (int ni = 0; ni < 2; ++ni)
                    acc[mi][ni] = __builtin_amdgcn_mfma_f32_16x16x32_bf16(
                        afrag[kk][mi], bfr[ni], acc[mi][ni], 0, 0, 0);
        }

        // streaming argmax update; strict '>' + ascending s keeps first-max semantics
        if (st == diagSt) {
            // diagonal tile: exclude s == t
#pragma unroll
            for (int mi = 0; mi < 2; ++mi) {
                const int tbase = rowBase + mi * 16 + lk * 4;
#pragma unroll
                for (int j = 0; j < 4; ++j) {
                    const int tj = tbase + j;
#pragma unroll
                    for (int ni = 0; ni < 2; ++ni) {
                        const float v = acc[mi][ni][j];
                        const int s = sBase + ni * 16 + lrow;
                        const bool ok = (s != tj) && (v > best[mi][j]);
                        best[mi][j] = ok ? v : best[mi][j];
                        bidx[mi][j] = ok ? s : bidx[mi][j];
                    }
                }
            }
        } else {
#pragma unroll
            for (int mi = 0; mi < 2; ++mi) {
#pragma unroll
                for (int j = 0; j < 4; ++j) {
#pragma unroll
                    for (int ni = 0; ni < 2; ++ni) {
                        const float v = acc[mi][ni][j];
                        const int s = sBase + ni * 16 + lrow;
                        const bool ok = (v > best[mi][j]);
                        best[mi][j] = ok ? v : best[mi][j];
                        bidx[mi][j] = ok ? s : bidx[mi][j];
                    }
                }
            }
        }
    }

    // reduce across the 16 lanes (lane&15) that share each C-row
    __shared__ float s_val[64][4];
    __shared__ int   s_idx[64][4];
#pragma unroll
    for (int mi = 0; mi < 2; ++mi) {
#pragma unroll
        for (int j = 0; j < 4; ++j) {
            float v = best[mi][j];
            int   ix = bidx[mi][j];
#pragma unroll
            for (int m = 8; m >= 1; m >>= 1) {
                float ov = __shfl_xor(v, m, 64);
                int   oi = __shfl_xor(ix, m, 64);
                if (ov > v || (ov == v && oi < ix)) { v = ov; ix = oi; }
            }
            if (lrow == 0) {
                const int rl = waveM * 32 + mi * 16 + lk * 4 + j;
                s_val[rl][waveN] = v;
                s_idx[rl][waveN] = ix;
            }
        }
    }
    __syncthreads();

    // reduce across the 4 N-waves; one thread per row
    if (tid < 64) {
        float v = s_val[tid][0];
        int  ix = s_idx[tid][0];
#pragma unroll
        for (int c = 1; c < 4; ++c) {
            float ov = s_val[tid][c];
            int   oi = s_idx[tid][c];
            if (ov > v || (ov == v && oi < ix)) { v = ov; ix = oi; }
        }
        nn_idx[batch * Tq + rowTile * 64 + tid] = ix;
    }
}

// ---------------- Phase 3: exact fp32 distance + loss ----------------
__global__ void loss_kernel(const float* __restrict__ x, const int* __restrict__ nn,
                            float* __restrict__ out) {
    const int lane = threadIdx.x & 63;
    const int wave = threadIdx.x >> 6;          // 4 waves / block
    const int gw = blockIdx.x * 4 + wave;       // 2048 global waves
    float lsum = 0.f;

    for (int row = gw; row < Bq * Tq; row += 2048) {
        const int b = row >> 12;
        const int t = row & (Tq - 1);
        const int s = nn[row];
        const float4* xt = (const float4*)(x + ((size_t)b * Tq + t) * Dq);
        const float4* xs = (const float4*)(x + ((size_t)b * Tq + s) * Dq);
        float4 a = xt[lane];
        float4 c = xs[lane];
        float dx = a.x - c.x + 1e-8f;
        float dy = a.y - c.y + 1e-8f;
        float dz = a.z - c.z + 1e-8f;
        float dw = a.w - c.w + 1e-8f;
        float sum = dx * dx + dy * dy + dz * dz + dw * dw;
#pragma unroll
        for (int m = 32; m >= 1; m >>= 1)
            sum += __shfl_xor(sum, m, 64);
        if (lane == 0)
            lsum += logf(sqrtf(sum) + 1e-8f);
    }

    __shared__ float red[4];
    if (lane == 0) red[wave] = lsum;
    __syncthreads();
    if (threadIdx.x == 0) {
        float s = red[0] + red[1] + red[2] + red[3];
        atomicAdd(out, -s * (1.0f / (Bq * Tq)));
    }
}

extern "C" void kernel_launch(void* const* d_in, const int* in_sizes, int n_in,
                              void* d_out, int out_size, void* d_ws, size_t ws_size,
                              hipStream_t stream) {
    const float* x = (const float*)d_in[0];
    float* out = (float*)d_out;

    unsigned short* xb = (unsigned short*)d_ws;                       // 16 MB bf16 copy
    int* nn = (int*)((char*)d_ws + (size_t)Bq * Tq * Dq * 2);         // 128 KB indices

    hipMemsetAsync(d_out, 0, sizeof(float), stream);

    const int n4 = Bq * Tq * Dq / 4;
    cvt_kernel<<<n4 / 256, 256, 0, stream>>>(x, xb);
    argmax_kernel<<<512, 512, 0, stream>>>(xb, nn);
    loss_kernel<<<512, 256, 0, stream>>>(x, nn, out);
}

// Round 3
// 104.330 us; speedup vs baseline: 2.6300x; 2.6300x over previous
//
#include <hip/hip_runtime.h>
#include <hip/hip_bf16.h>
#include <math.h>

// KoLeo loss: B=8, T=4096, D=256 fp32 input.
// Phase 1: convert x -> bf16 (ws)
// Phase 2: per-batch Gram X·X^T via bf16 MFMA; A (256 rows) register-resident,
//          B staged via global_load_lds (swizzled) and streamed over s;
//          streaming per-row argmax merged across s-halves with atomicMax
//          on packed (orderable-float, ~idx) u64 keys.
// Phase 3: exact fp32 distances to argmax neighbor, loss = -mean(log(dist+eps))

#define Bq 8
#define Tq 4096
#define Dq 256
#define SBLK 64          // s-columns staged per tile
#define NST 32           // tiles per s-half: 2048 / 64
#define S_HALF 2048

typedef __attribute__((ext_vector_type(8))) short bf16x8;
typedef __attribute__((ext_vector_type(4))) float f32x4;
typedef unsigned int u32;
typedef unsigned long long u64;

__device__ __forceinline__ unsigned short f2bf(float f) {
    unsigned int u = __float_as_uint(f);
    unsigned int r = (u + 0x7fffu + ((u >> 16) & 1u)) >> 16;   // RNE
    return (unsigned short)r;
}

__device__ __forceinline__ void gload_lds16(const void* g, void* l) {
    typedef __attribute__((address_space(1))) const unsigned int gu32;
    typedef __attribute__((address_space(3))) unsigned int lu32;
    __builtin_amdgcn_global_load_lds((gu32*)g, (lu32*)l, 16, 0, 0);
}

// ---------------- Phase 1: fp32 -> bf16 ----------------
__global__ void cvt_kernel(const float* __restrict__ x, unsigned short* __restrict__ xb) {
    int i = blockIdx.x * blockDim.x + threadIdx.x;  // one float4 per thread
    const int n4 = Bq * Tq * Dq / 4;
    if (i < n4) {
        float4 v = ((const float4*)x)[i];
        ushort4 o;
        o.x = f2bf(v.x); o.y = f2bf(v.y); o.z = f2bf(v.z); o.w = f2bf(v.w);
        ((ushort4*)xb)[i] = o;
    }
}

// ---------------- Phase 2: Gram + streaming argmax ----------------
// Grid: 256 blocks = 8 batches x 16 row-tiles(256 rows) x 2 s-halves(2048 cols).
//   batch = bid & 7  -> same-batch blocks share an XCD L2 (batch panel = 2 MB bf16).
// Block: 512 threads = 8 waves as 4M x 2N. Wave tile: 64 rows (mi=4) x 32 cols (ni=2).
// A fragments register-resident: afrag[8][4] = 128 VGPR (rows fixed per block).
// B: LDS double-buffer 2 x 64 x 512 B = 64 KB, staged with global_load_lds width=16,
//    XOR-swizzled (linear LDS dest + pre-swizzled global src + swizzled ds_read).
// mfma_f32_16x16x32_bf16 C/D layout: col = lane&15, row = (lane>>4)*4 + reg (verified).
__global__ __launch_bounds__(512, 2)
void argmax_kernel(const unsigned short* __restrict__ xb, u64* __restrict__ keys) {
    const int bid   = blockIdx.x;
    const int batch = bid & 7;
    const int rt    = (bid >> 3) & 15;     // row-tile 0..15 (256 rows each)
    const int sh    = bid >> 7;            // s-half 0..1
    const int tid   = threadIdx.x;
    const int lane  = tid & 63;
    const int wave  = tid >> 6;            // 0..7
    const int waveM = wave >> 1;           // 0..3
    const int waveN = wave & 1;            // 0..1
    const int lrow  = lane & 15;           // A-row / B-col / C-col
    const int lk    = lane >> 4;           // k-group / C row-group

    const unsigned short* xB = xb + (size_t)batch * Tq * Dq;
    const char* xBb = (const char*)xB;                 // byte view, row stride 512 B
    const int rowBase = rt * 256 + waveM * 64;         // wave's 64 rows
    const int sHalfBase = sh * S_HALF;

    __shared__ char smem[2 * SBLK * 512];              // 64 KB double buffer

    // ---- A fragments, register resident: afrag[kk][mi] = 128 VGPR ----
    bf16x8 afrag[8][4];
#pragma unroll
    for (int mi = 0; mi < 4; ++mi) {
        const unsigned short* rp = xB + (size_t)(rowBase + mi * 16 + lrow) * Dq + lk * 8;
#pragma unroll
        for (int kk = 0; kk < 8; ++kk)
            afrag[kk][mi] = *(const bf16x8*)(rp + kk * 32);
    }

    // ---- staging: tile st (64 s-rows x 512 B) into buffer buf ----
    // LDS linear slot ls = s_local*512 + q holds global byte (q ^ ((s_local&7)<<4))
    // of row (S0 + s_local): linear dest + inverse-swizzled source (rule #21).
    auto STAGE = [&](int st, int buf) {
        const int S0 = sHalfBase + st * SBLK;
        char* lbase = smem + buf * (SBLK * 512);
#pragma unroll
        for (int it = 0; it < 4; ++it) {
            const int ls = it * 8192 + tid * 16;       // 0..32767, wave-contiguous
            const int s_local = ls >> 9;
            const int q = ls & 511;
            const char* g = xBb + (size_t)(S0 + s_local) * 512 + (q ^ ((s_local & 7) << 4));
            gload_lds16(g, lbase + ls);
        }
    };

    float best[4][4];   // [mi][j]
    int   bidxv[4][4];
#pragma unroll
    for (int mi = 0; mi < 4; ++mi)
#pragma unroll
        for (int j = 0; j < 4; ++j) { best[mi][j] = -1e30f; bidxv[mi][j] = 0; }

    STAGE(0, 0);
    asm volatile("s_waitcnt vmcnt(0)");
    __syncthreads();

    for (int st = 0; st < NST; ++st) {
        const int buf = st & 1;
        if (st + 1 < NST) STAGE(st + 1, buf ^ 1);

        const char* lbase = smem + buf * (SBLK * 512);
        const int S0 = sHalfBase + st * SBLK;
        const int sW = waveN * 32;                     // wave's local col base

        f32x4 acc[4][2];
#pragma unroll
        for (int mi = 0; mi < 4; ++mi)
#pragma unroll
            for (int ni = 0; ni < 2; ++ni)
                acc[mi][ni] = (f32x4){0.f, 0.f, 0.f, 0.f};

#pragma unroll
        for (int kk = 0; kk < 8; ++kk) {
            bf16x8 bfr[2];
#pragma unroll
            for (int ni = 0; ni < 2; ++ni) {
                const int s_local = sW + ni * 16 + lrow;
                const int kbyte = kk * 64 + lk * 16;
                bfr[ni] = *(const bf16x8*)(lbase + s_local * 512 +
                                           (kbyte ^ ((s_local & 7) << 4)));
            }
#pragma unroll
            for (int mi = 0; mi < 4; ++mi)
#pragma unroll
                for (int ni = 0; ni < 2; ++ni)
                    acc[mi][ni] = __builtin_amdgcn_mfma_f32_16x16x32_bf16(
                        afrag[kk][mi], bfr[ni], acc[mi][ni], 0, 0, 0);
        }

        // streaming argmax update (diag always guarded; strict '>' + ascending s)
#pragma unroll
        for (int mi = 0; mi < 4; ++mi) {
            const int tbase = rowBase + mi * 16 + lk * 4;
#pragma unroll
            for (int j = 0; j < 4; ++j) {
                const int tj = tbase + j;
#pragma unroll
                for (int ni = 0; ni < 2; ++ni) {
                    const float v = acc[mi][ni][j];
                    const int s = S0 + sW + ni * 16 + lrow;
                    const bool ok = (s != tj) && (v > best[mi][j]);
                    best[mi][j] = ok ? v : best[mi][j];
                    bidxv[mi][j] = ok ? s : bidxv[mi][j];
                }
            }
        }

        asm volatile("s_waitcnt vmcnt(0)");
        __syncthreads();
    }

    // ---- reduce across the 16 lanes sharing each C-row, then global atomicMax ----
#pragma unroll
    for (int mi = 0; mi < 4; ++mi) {
#pragma unroll
        for (int j = 0; j < 4; ++j) {
            float v = best[mi][j];
            int   ix = bidxv[mi][j];
#pragma unroll
            for (int m = 8; m >= 1; m >>= 1) {
                float ov = __shfl_xor(v, m, 64);
                int   oi = __shfl_xor(ix, m, 64);
                if (ov > v || (ov == v && oi < ix)) { v = ov; ix = oi; }
            }
            if (lrow == 0) {
                const int row = rowBase + mi * 16 + lk * 4 + j;
                const u32 u = __float_as_uint(v);
                const u32 o = (u & 0x80000000u) ? ~u : (u | 0x80000000u);  // orderable
                const u64 key = ((u64)o << 32) | (u32)(~ix);               // ties: low idx
                atomicMax(keys + batch * Tq + row, key);
            }
        }
    }
}

// ---------------- Phase 3: exact fp32 distance + loss ----------------
__global__ void loss_kernel(const float* __restrict__ x, const u64* __restrict__ keys,
                            float* __restrict__ out) {
    const int lane = threadIdx.x & 63;
    const int wave = threadIdx.x >> 6;          // 4 waves / block
    const int gw = blockIdx.x * 4 + wave;       // 2048 global waves
    float lsum = 0.f;

    for (int row = gw; row < Bq * Tq; row += 2048) {
        const int b = row >> 12;
        const int t = row & (Tq - 1);
        const int s = (int)((u32)(~keys[row]));
        const float4* xt = (const float4*)(x + ((size_t)b * Tq + t) * Dq);
        const float4* xs = (const float4*)(x + ((size_t)b * Tq + s) * Dq);
        float4 a = xt[lane];
        float4 c = xs[lane];
        float dx = a.x - c.x + 1e-8f;
        float dy = a.y - c.y + 1e-8f;
        float dz = a.z - c.z + 1e-8f;
        float dw = a.w - c.w + 1e-8f;
        float sum = dx * dx + dy * dy + dz * dz + dw * dw;
#pragma unroll
        for (int m = 32; m >= 1; m >>= 1)
            sum += __shfl_xor(sum, m, 64);
        if (lane == 0)
            lsum += logf(sqrtf(sum) + 1e-8f);
    }

    __shared__ float red[4];
    if (lane == 0) red[wave] = lsum;
    __syncthreads();
    if (threadIdx.x == 0) {
        float s = red[0] + red[1] + red[2] + red[3];
        atomicAdd(out, -s * (1.0f / (Bq * Tq)));
    }
}

extern "C" void kernel_launch(void* const* d_in, const int* in_sizes, int n_in,
                              void* d_out, int out_size, void* d_ws, size_t ws_size,
                              hipStream_t stream) {
    const float* x = (const float*)d_in[0];
    float* out = (float*)d_out;

    unsigned short* xb = (unsigned short*)d_ws;                        // 16 MB bf16 copy
    u64* keys = (u64*)((char*)d_ws + (size_t)Bq * Tq * Dq * 2);        // 256 KB keys

    hipMemsetAsync(d_out, 0, sizeof(float), stream);
    hipMemsetAsync(keys, 0, (size_t)Bq * Tq * sizeof(u64), stream);    // key=0 < any real

    const int n4 = Bq * Tq * Dq / 4;
    cvt_kernel<<<n4 / 256, 256, 0, stream>>>(x, xb);
    argmax_kernel<<<256, 512, 0, stream>>>(xb, keys);
    loss_kernel<<<512, 256, 0, stream>>>(x, keys, out);
}